// Round 17
// baseline (61.575 us; speedup 1.0000x reference)
//
#include <hip/hip_runtime.h>
#include <hip/hip_bf16.h>

// Problem constants (from reference)
#define F_DIM 2048
#define B_DIM 4
#define DIM 128
#define QKV_COLS 384
#define HEADS 8
#define DH 16

#define SHIFT2 14.4269504f   // 10 * log2(e)  (softmax fixed shift, exp2 domain)
#define QSCALE 0.360673760f  // 0.25 * log2(e) (folded into W_q at bf16 conversion)

typedef float float4v __attribute__((ext_vector_type(4)));
typedef short short4v __attribute__((ext_vector_type(4)));

static __device__ __forceinline__ unsigned short f2bf(float v) {
    __hip_bfloat16 h = __float2bfloat16(v);
    return __builtin_bit_cast(unsigned short, h);
}
static __device__ __forceinline__ float bf2f(unsigned short u) {
    unsigned int w = ((unsigned int)u) << 16;
    return __builtin_bit_cast(float, w);
}

// pack 4 fp32 -> 4 bf16 (RNE) via v_cvt_pk_bf16_f32 (no builtin on gfx950).
static __device__ __forceinline__ short4v pack_bf16x4(float a, float b, float c, float d) {
    unsigned plo, phi;
    asm("v_cvt_pk_bf16_f32 %0, %1, %2" : "=v"(plo) : "v"(a), "v"(b));
    asm("v_cvt_pk_bf16_f32 %0, %1, %2" : "=v"(phi) : "v"(c), "v"(d));
    uint2 u{plo, phi};
    return __builtin_bit_cast(short4v, u);
}

// ws layout (bytes):
//   [0,   4M): attn fp32 [8192][128]
//   [4M,  6M): Qbf ushort [32][2048][16]       (Q pre-scaled via Wbf)
//   [6M,  8M): Kbf ushort [32][2048][16]
//   [8M, 10M): VTt ushort [32][128][16][16]    (V^T in 16-key tiles)
//   [10M, +96K): Wbf ushort [384][128]         (rows 0..127 pre-scaled QSCALE)
//   [10M+128K, +32K): W0h ushort [128][128]
//   [10M+192K, +32K): W0l ushort [128][128]    (bf16 residual of W0)
// total < 10.3 MiB.

// ---------------------------------------------------------------------------
// Kernel 0: weight conversion only (x split is fused into qkv_mfma).
// Wqkv -> Wbf (QSCALE folded into Q rows), W0 -> W0h+W0l.
// NOTE: folding this into the MFMA kernels failed twice (rounds 12/13, NaN,
// both asm-pack and compiler-cast variants) — keep the separate kernel.
// Attn unroll 4 also failed in isolation (round 15) — keep unroll 2.
// ---------------------------------------------------------------------------
__global__ __launch_bounds__(256) void convert_kernel(const float* __restrict__ Wqkv,
                                                      const float* __restrict__ W0,
                                                      unsigned short* __restrict__ Wbf,
                                                      unsigned short* __restrict__ W0h,
                                                      unsigned short* __restrict__ W0l) {
    if (blockIdx.x < 24) { // Wqkv: 49,152 elements, 8 per thread, 24 blocks
        const int t = blockIdx.x * 256 + threadIdx.x;
        const size_t base = (size_t)t * 8;
        const int c = (int)(base >> 7); // W row = output column
        const float scale = (c < 128) ? QSCALE : 1.f;
        float v[8];
        *(float4*)(v)     = *(const float4*)(Wqkv + base);
        *(float4*)(v + 4) = *(const float4*)(Wqkv + base + 4);
        unsigned short h[8];
#pragma unroll
        for (int j = 0; j < 8; ++j) h[j] = f2bf(v[j] * scale);
        *(uint4*)(Wbf + base) = *(const uint4*)h;
    } else { // W0: 16,384 elements, hi/lo split, 8 blocks
        const int t = (blockIdx.x - 24) * 256 + threadIdx.x;
        const size_t base = (size_t)t * 8;
        float v[8];
        *(float4*)(v)     = *(const float4*)(W0 + base);
        *(float4*)(v + 4) = *(const float4*)(W0 + base + 4);
        unsigned short h[8], l[8];
#pragma unroll
        for (int j = 0; j < 8; ++j) {
            h[j] = f2bf(v[j]);
            l[j] = f2bf(v[j] - bf2f(h[j]));
        }
        *(uint4*)(W0h + base) = *(const uint4*)h;
        *(uint4*)(W0l + base) = *(const uint4*)l;
    }
}

// ---------------------------------------------------------------------------
// Kernel A: qkv GEMM via MFMA. x loaded fp32 and split to bf16 hi+lo
// IN-REGISTER (proven proj_mfma pattern); W read as pre-converted bf16.
// Wave = 16 rows x 96 cols (6 col-tiles), K=128 (8 k-frags): 96 MFMAs/wave.
// ---------------------------------------------------------------------------
__global__ __launch_bounds__(256) void qkv_mfma_kernel(const float* __restrict__ x,
                                                       const unsigned short* __restrict__ Wbf,
                                                       unsigned short* __restrict__ Qbf,
                                                       unsigned short* __restrict__ Kbf,
                                                       unsigned short* __restrict__ VTt) {
    const int lane = threadIdx.x & 63;
    const int wid = threadIdx.x >> 6;             // 0..3
    const int rbase = blockIdx.x * 64 + wid * 16; // x-row tile base
    const int ctbase = blockIdx.y * 6;            // col-tile base (of 24)
    const int lo = lane & 15, hi = lane >> 4;

    // B fragments: x rows fp32 -> split bf16 hi/lo in-register.
    const float* xp = x + (size_t)(rbase + lo) * DIM + hi * 4;
    short4v xfh[8], xfl[8];
#pragma unroll
    for (int kb = 0; kb < 8; ++kb) {
        float4 xv = *(const float4*)(xp + kb * 16);
        short4v xh = pack_bf16x4(xv.x, xv.y, xv.z, xv.w);
        xfh[kb] = xh;
        xfl[kb] = pack_bf16x4(xv.x - bf2f((unsigned short)xh[0]),
                              xv.y - bf2f((unsigned short)xh[1]),
                              xv.z - bf2f((unsigned short)xh[2]),
                              xv.w - bf2f((unsigned short)xh[3]));
    }

    float4v d[6];
#pragma unroll
    for (int j = 0; j < 6; ++j) d[j] = (float4v){0.f, 0.f, 0.f, 0.f};

    const unsigned short* wp = Wbf + (size_t)(ctbase * 16 + lo) * DIM + hi * 4;
#pragma unroll
    for (int j = 0; j < 6; ++j) {
#pragma unroll
        for (int kb = 0; kb < 8; ++kb) {
            short4v wf = *(const short4v*)(wp + (size_t)j * 16 * DIM + kb * 16);
            d[j] = __builtin_amdgcn_mfma_f32_16x16x16bf16_1k(wf, xfh[kb], d[j], 0, 0, 0);
            d[j] = __builtin_amdgcn_mfma_f32_16x16x16bf16_1k(wf, xfl[kb], d[j], 0, 0, 0);
        }
    }

    const int i = rbase + lo;
    const int f = i >> 2, bb = i & 3;
#pragma unroll
    for (int j = 0; j < 6; ++j) {
        const int ct = ctbase + j; // 0..23
        short4v pv = pack_bf16x4(d[j][0], d[j][1], d[j][2], d[j][3]);
        if (ct < 8) {            // Q, head = ct
            unsigned short* dst = Qbf + ((size_t)(bb * 8 + ct) * F_DIM + f) * DH + hi * 4;
            *(uint2*)dst = __builtin_bit_cast(uint2, pv);
        } else if (ct < 16) {    // K, head = ct-8
            unsigned short* dst = Kbf + ((size_t)(bb * 8 + (ct - 8)) * F_DIM + f) * DH + hi * 4;
            *(uint2*)dst = __builtin_bit_cast(uint2, pv);
        } else {                 // V^T tiles: [bh][kt=f>>4][dd][ft=f&15]
            const int hh = ct - 16;
            unsigned short* dst = VTt
                + (((size_t)(bb * 8 + hh) * 128 + (f >> 4)) * 16) * 16 + (f & 15);
#pragma unroll
            for (int r = 0; r < 4; ++r) {
                const int dd = hi * 4 + r;
                dst[(size_t)dd * 16] = (unsigned short)pv[r];
            }
        }
    }
}

// ---------------------------------------------------------------------------
// Kernel B: MFMA flash attention, split-K 8 for occupancy. Block = 8 waves =
// 8 key-chunks (ch = wid) sharing one 64-query group; grid (32, 32) = 1024
// blocks -> 4 blocks/CU, 32 waves/CU. Shuffle-based l; NO ones-MFMA;
// unroll 2 (unroll 4 convicted, round 15).
// ---------------------------------------------------------------------------
__global__ __launch_bounds__(512, 4) void attn_mfma_kernel(const unsigned short* __restrict__ Qbf,
                                                           const unsigned short* __restrict__ Kbf,
                                                           const unsigned short* __restrict__ VTt,
                                                           float* __restrict__ attn) {
    __shared__ float4v comb[7][64][5]; // 35 KiB split-K combine

    const int bh = blockIdx.y;
    const int b = bh >> 3, h = bh & 7;
    const int lane = threadIdx.x & 63;
    const int ch = threadIdx.x >> 6;   // key chunk 0..7 (256 keys each)
    const int q0 = blockIdx.x * 64;
    const int lo = lane & 15, hi = lane >> 4;

    const unsigned short* Qp = Qbf + ((size_t)bh * F_DIM + q0 + lo) * DH + hi * 4;
    const short4v qf0 = *(const short4v*)(Qp);
    const short4v qf1 = *(const short4v*)(Qp + 16 * DH);
    const short4v qf2 = *(const short4v*)(Qp + 32 * DH);
    const short4v qf3 = *(const short4v*)(Qp + 48 * DH);

    const unsigned short* Kp = Kbf + (size_t)bh * F_DIM * DH
                             + (size_t)ch * 256 * DH + (size_t)lo * DH + hi * 4;
    const unsigned short* Vp = VTt + ((size_t)bh * 128 + ch * 16) * 256
                             + lo * 16 + hi * 4;

    float4v acc0 = {0.f, 0.f, 0.f, 0.f};
    float4v acc1 = {0.f, 0.f, 0.f, 0.f};
    float4v acc2 = {0.f, 0.f, 0.f, 0.f};
    float4v acc3 = {0.f, 0.f, 0.f, 0.f};
    float4v la0 = {0.f, 0.f, 0.f, 0.f};
    float4v la1 = {0.f, 0.f, 0.f, 0.f};
    float4v la2 = {0.f, 0.f, 0.f, 0.f};
    float4v la3 = {0.f, 0.f, 0.f, 0.f};
    const float4v cinit = {-SHIFT2, -SHIFT2, -SHIFT2, -SHIFT2};

#pragma unroll 2
    for (int kt = 0; kt < 16; ++kt) {
        const short4v kf = *(const short4v*)(Kp + kt * 256);
        const short4v vf = *(const short4v*)(Vp + kt * 256);

        float4v s0 = __builtin_amdgcn_mfma_f32_16x16x16bf16_1k(kf, qf0, cinit, 0, 0, 0);
        float4v s1 = __builtin_amdgcn_mfma_f32_16x16x16bf16_1k(kf, qf1, cinit, 0, 0, 0);
        float4v s2 = __builtin_amdgcn_mfma_f32_16x16x16bf16_1k(kf, qf2, cinit, 0, 0, 0);
        float4v s3 = __builtin_amdgcn_mfma_f32_16x16x16bf16_1k(kf, qf3, cinit, 0, 0, 0);

        float p00 = __builtin_amdgcn_exp2f(s0[0]), p01 = __builtin_amdgcn_exp2f(s0[1]);
        float p02 = __builtin_amdgcn_exp2f(s0[2]), p03 = __builtin_amdgcn_exp2f(s0[3]);
        float p10 = __builtin_amdgcn_exp2f(s1[0]), p11 = __builtin_amdgcn_exp2f(s1[1]);
        float p12 = __builtin_amdgcn_exp2f(s1[2]), p13 = __builtin_amdgcn_exp2f(s1[3]);
        float p20 = __builtin_amdgcn_exp2f(s2[0]), p21 = __builtin_amdgcn_exp2f(s2[1]);
        float p22 = __builtin_amdgcn_exp2f(s2[2]), p23 = __builtin_amdgcn_exp2f(s2[3]);
        float p30 = __builtin_amdgcn_exp2f(s3[0]), p31 = __builtin_amdgcn_exp2f(s3[1]);
        float p32 = __builtin_amdgcn_exp2f(s3[2]), p33 = __builtin_amdgcn_exp2f(s3[3]);

        la0[0] += p00; la0[1] += p01; la0[2] += p02; la0[3] += p03;
        la1[0] += p10; la1[1] += p11; la1[2] += p12; la1[3] += p13;
        la2[0] += p20; la2[1] += p21; la2[2] += p22; la2[3] += p23;
        la3[0] += p30; la3[1] += p31; la3[2] += p32; la3[3] += p33;

        short4v pa0 = pack_bf16x4(p00, p01, p02, p03);
        short4v pa1 = pack_bf16x4(p10, p11, p12, p13);
        short4v pa2 = pack_bf16x4(p20, p21, p22, p23);
        short4v pa3 = pack_bf16x4(p30, p31, p32, p33);

        acc0 = __builtin_amdgcn_mfma_f32_16x16x16bf16_1k(pa0, vf, acc0, 0, 0, 0);
        acc1 = __builtin_amdgcn_mfma_f32_16x16x16bf16_1k(pa1, vf, acc1, 0, 0, 0);
        acc2 = __builtin_amdgcn_mfma_f32_16x16x16bf16_1k(pa2, vf, acc2, 0, 0, 0);
        acc3 = __builtin_amdgcn_mfma_f32_16x16x16bf16_1k(pa3, vf, acc3, 0, 0, 0);
    }

    float l0 = (la0[0] + la0[1]) + (la0[2] + la0[3]);
    float l1 = (la1[0] + la1[1]) + (la1[2] + la1[3]);
    float l2 = (la2[0] + la2[1]) + (la2[2] + la2[3]);
    float l3 = (la3[0] + la3[1]) + (la3[2] + la3[3]);

    if (ch) {
        float4v* pw = comb[ch - 1][lane];
        pw[0] = acc0; pw[1] = acc1; pw[2] = acc2; pw[3] = acc3;
        float4v lv = {l0, l1, l2, l3};
        pw[4] = lv;
    }
    __syncthreads();
    if (!ch) {
#pragma unroll
        for (int part = 0; part < 7; ++part) {
            const float4v* pr = comb[part][lane];
            acc0 += pr[0]; acc1 += pr[1]; acc2 += pr[2]; acc3 += pr[3];
            float4v tl = pr[4];
            l0 += tl[0]; l1 += tl[1]; l2 += tl[2]; l3 += tl[3];
        }

#define STORE_FRAG(ACC, L, FR)                                                  \
        {                                                                       \
            float l = L;                                                        \
            l += __shfl_xor(l, 16);                                             \
            l += __shfl_xor(l, 32);                                             \
            float inv = 1.f / l; /* valid for q = lo */                         \
            _Pragma("unroll")                                                   \
            for (int r = 0; r < 4; ++r) {                                       \
                int q = hi * 4 + r;                                             \
                float invq = __shfl(inv, q);                                    \
                int f = q0 + (FR) * 16 + q;                                     \
                attn[((size_t)f * B_DIM + b) * DIM + h * DH + lo] = ACC[r] * invq; \
            }                                                                   \
        }
        STORE_FRAG(acc0, l0, 0)
        STORE_FRAG(acc1, l1, 1)
        STORE_FRAG(acc2, l2, 2)
        STORE_FRAG(acc3, l3, 3)
#undef STORE_FRAG
    }
}

// ---------------------------------------------------------------------------
// Kernel C: proj via MFMA, split precision (round-10/11/14 passing form).
// ---------------------------------------------------------------------------
__global__ __launch_bounds__(256) void proj_mfma_kernel(const float* __restrict__ attn,
                                                        const unsigned short* __restrict__ W0h,
                                                        const unsigned short* __restrict__ W0l,
                                                        const float* __restrict__ b0,
                                                        float* __restrict__ out) {
    const int lane = threadIdx.x & 63;
    const int wid = threadIdx.x >> 6;             // 0..3
    const int rbase = blockIdx.x * 64 + wid * 16; // attn-row tile base
    const int cbase = blockIdx.y * 32;            // col base
    const int lo = lane & 15, hi = lane >> 4;

    const float* ap = attn + (size_t)(rbase + lo) * DIM + hi * 4;
    short4v afh[8], afl[8];
#pragma unroll
    for (int kb = 0; kb < 8; ++kb) {
        float4 av = *(const float4*)(ap + kb * 16);
        short4v ah = pack_bf16x4(av.x, av.y, av.z, av.w);
        afh[kb] = ah;
        afl[kb] = pack_bf16x4(av.x - bf2f((unsigned short)ah[0]),
                              av.y - bf2f((unsigned short)ah[1]),
                              av.z - bf2f((unsigned short)ah[2]),
                              av.w - bf2f((unsigned short)ah[3]));
    }

    float4v d[2];
#pragma unroll
    for (int j = 0; j < 2; ++j) d[j] = (float4v){0.f, 0.f, 0.f, 0.f};

    const unsigned short* wph = W0h + (size_t)(cbase + lo) * DIM + hi * 4;
    const unsigned short* wpl = W0l + (size_t)(cbase + lo) * DIM + hi * 4;
#pragma unroll
    for (int j = 0; j < 2; ++j) {
#pragma unroll
        for (int kb = 0; kb < 8; ++kb) {
            short4v wh = *(const short4v*)(wph + (size_t)j * 16 * DIM + kb * 16);
            short4v wl = *(const short4v*)(wpl + (size_t)j * 16 * DIM + kb * 16);
            d[j] = __builtin_amdgcn_mfma_f32_16x16x16bf16_1k(wh, afh[kb], d[j], 0, 0, 0);
            d[j] = __builtin_amdgcn_mfma_f32_16x16x16bf16_1k(wh, afl[kb], d[j], 0, 0, 0);
            d[j] = __builtin_amdgcn_mfma_f32_16x16x16bf16_1k(wl, afh[kb], d[j], 0, 0, 0);
        }
    }

    const int row = rbase + lo;
#pragma unroll
    for (int j = 0; j < 2; ++j) {
        const int col4 = cbase + j * 16 + hi * 4;
        float4 bias = *(const float4*)(b0 + col4);
        float4 o;
        o.x = d[j][0] + bias.x;
        o.y = d[j][1] + bias.y;
        o.z = d[j][2] + bias.z;
        o.w = d[j][3] + bias.w;
        *(float4*)(out + (size_t)row * DIM + col4) = o;
    }
}

// ---------------------------------------------------------------------------
extern "C" void kernel_launch(void* const* d_in, const int* in_sizes, int n_in,
                              void* d_out, int out_size, void* d_ws, size_t ws_size,
                              hipStream_t stream) {
    const float* x    = (const float*)d_in[0]; // (2048,4,128)
    const float* Wqkv = (const float*)d_in[1]; // (384,128)
    const float* W0   = (const float*)d_in[2]; // (128,128)
    const float* b0   = (const float*)d_in[3]; // (128,)
    float* out = (float*)d_out;                // (2048,4,128)

    char* ws = (char*)d_ws;
    float* attn          = (float*)(ws);                          // 4 MiB
    unsigned short* Qbf  = (unsigned short*)(ws + (4u << 20));    // 2 MiB
    unsigned short* Kbf  = (unsigned short*)(ws + (6u << 20));    // 2 MiB
    unsigned short* VTt  = (unsigned short*)(ws + (8u << 20));    // 2 MiB
    unsigned short* Wbf  = (unsigned short*)(ws + (10u << 20));            // 96 KiB
    unsigned short* W0h  = (unsigned short*)(ws + (10u << 20) + (128u << 10)); // 32 KiB
    unsigned short* W0l  = (unsigned short*)(ws + (10u << 20) + (192u << 10)); // 32 KiB

    convert_kernel<<<32, 256, 0, stream>>>(Wqkv, W0, Wbf, W0h, W0l);
    qkv_mfma_kernel<<<dim3(128, 4), 256, 0, stream>>>(x, Wbf, Qbf, Kbf, VTt);
    attn_mfma_kernel<<<dim3(32, 32), 512, 0, stream>>>(Qbf, Kbf, VTt, attn);
    proj_mfma_kernel<<<dim3(128, 4), 256, 0, stream>>>(attn, W0h, W0l, b0, out);
}